// Round 5
// baseline (120.456 us; speedup 1.0000x reference)
//
#include <hip/hip_runtime.h>
#include <hip/hip_bf16.h>

// Model_10514079940941 — fused single kernel. fp32 inputs, fp32 outputs
// (R3==R4 bit-identical error proved the math; the bug was bf16 output stores).
// One block per gaussian (1024 blocks x 256 threads). All 1024 conics staged
// in 32 KB LDS; pairwise phase 8-way chunked; MLP + finalize in-block.

#define NG 1024

__global__ __launch_bounds__(256) void k_fused(
    const float* __restrict__ means, const float* __restrict__ u,
    const float* __restrict__ scal, const float* __restrict__ trans,
    const float* __restrict__ opac,
    const float* __restrict__ convW, const float* __restrict__ convb,
    const float* __restrict__ embW,  const float* __restrict__ embb,
    const float* __restrict__ l1W,   const float* __restrict__ l1b,
    const float* __restrict__ oWs,  const float* __restrict__ obs,
    const float* __restrict__ oWt,  const float* __restrict__ obt,
    const float* __restrict__ oWsc, const float* __restrict__ obsc,
    const float* __restrict__ oWtf, const float* __restrict__ obtf,
    float* __restrict__ out)
{
    __shared__ float gd[NG * 8];      // 32 KB: mx,my,A,B | C,trC,alpha*u,0
    __shared__ float pus[8][32];
    __shared__ float plap[8][32];
    __shared__ float simg[80];        // 75 used: u_s(25), lap(25), bc(25)
    __shared__ float hin[4][80];
    __shared__ float hv[4][80];
    __shared__ float outs[8];

    const int t = threadIdx.x;
    const int n = blockIdx.x;

    // ---------------- Phase 0: prep all gaussians into LDS ------------------
    for (int g = t; g < NG; g += 256) {
        float gmx = means[2*g], gmy = means[2*g+1];
        float s0  = scal[2*g],  s1  = scal[2*g+1];
        float tt  = trans[g];
        float c00 = s0*s0, c01 = s0*tt, c11 = tt*tt + s1*s1;
        float idet = 1.0f / (c00*c11 - c01*c01);
        float A = c11*idet, B = -c01*idet, C = c00*idet;
        float alpha = 1.0f / (1.0f + __expf(-opac[g]));
        float4* dst = (float4*)(gd + g*8);
        dst[0] = make_float4(gmx, gmy, A, B);
        dst[1] = make_float4(C, A + C, alpha * u[g], 0.0f);
    }
    __syncthreads();

    const float mx = means[2*n], my = means[2*n+1];

    // ---------------- Phase 1: pairwise sums, 8-way chunked -----------------
    {
        int s = t & 31, c = t >> 5;   // wave spans 2 chunks -> <=2-way LDS alias (free)
        if (s < 25) {
            int si = s / 5, sj = s - si * 5;
            float sx = mx + (float)(si - 2) * 0.01f;
            float sy = my + (float)(sj - 2) * 0.01f;
            float us = 0.0f, lp = 0.0f;
            const float* gp = gd + c * 128 * 8;
            #pragma unroll 4
            for (int i = 0; i < 128; ++i) {
                float4 a = *(const float4*)(gp + i*8);
                float4 b = *(const float4*)(gp + i*8 + 4);
                float dx = sx - a.x, dy = sy - a.y;
                float Cq0 = a.z*dx + a.w*dy;
                float Cq1 = a.w*dx + b.x*dy;
                float q   = dx*Cq0 + dy*Cq1;
                float e   = __expf(-0.5f*q) * b.z;     // G * alpha * u
                us += e;
                lp += e * (Cq0*Cq0 + Cq1*Cq1 - b.y);
            }
            pus[c][s] = us; plap[c][s] = lp;
        }
    }
    __syncthreads();

    // ---------------- Phase A: reduce chunks -> img[75] ---------------------
    if (t < 25) {
        float us = 0.0f, lp = 0.0f;
        #pragma unroll
        for (int c = 0; c < 8; ++c) { us += pus[c][t]; lp += plap[c][t]; }
        int si = t / 5, sj = t - si * 5;
        float sx = mx + (float)(si - 2) * 0.01f;
        float sy = my + (float)(sj - 2) * 0.01f;
        simg[t]      = us;
        simg[25 + t] = lp;
        simg[50 + t] = (fabsf(sx) < 1.0f && fabsf(sy) < 1.0f) ? 1.0f : 0.0f;
    }
    __syncthreads();

    // ---------------- Phase B: conv (200 outs) + emb (120 outs) -------------
    if (t < 200) {
        int k = t / 50, o = t - k * 50;
        const float* w = convW + (size_t)(k * 50 + o) * 75;
        float acc = convb[k * 50 + o];
        #pragma unroll 5
        for (int j = 0; j < 75; ++j) acc += simg[j] * w[j];
        hin[k][o] = tanhf(acc);
    } else {
        float inp[7] = { mx, my, u[n], scal[2*n], scal[2*n+1], trans[n], opac[n] };
        for (int idx = t - 200; idx < 120; idx += 56) {
            int k = idx / 30, g = idx - k * 30;
            float acc = embb[k * 30 + g];
            #pragma unroll
            for (int f = 0; f < 7; ++f) acc += inp[f] * embW[(k*7 + f)*30 + g];
            hin[k][50 + g] = tanhf(acc);
        }
    }
    __syncthreads();

    // ---------------- Phase C: l1 (4 x 80 outs) -----------------------------
    for (int idx = t; idx < 320; idx += 256) {
        int k = idx / 80, g = idx - k * 80;
        float acc = l1b[k * 80 + g];
        #pragma unroll 8
        for (int f = 0; f < 80; ++f)
            acc += hin[k][f] * l1W[(k*80 + f)*80 + g];
        hv[k][g] = tanhf(acc);
    }
    __syncthreads();

    // ---------------- Phase D: output heads (6 dots of 80) ------------------
    if (t < 6) {
        const float* W; const float* bb; int k, j, stride;
        if (t == 0)      { W = oWs;  bb = obs;  k = 0; j = 0;     stride = 1; }
        else if (t < 3)  { W = oWt;  bb = obt;  k = 1; j = t - 1; stride = 2; }
        else if (t < 5)  { W = oWsc; bb = obsc; k = 2; j = t - 3; stride = 2; }
        else             { W = oWtf; bb = obtf; k = 3; j = 0;     stride = 1; }
        float acc = bb[j];
        #pragma unroll 8
        for (int f = 0; f < 80; ++f) acc += hv[k][f] * W[f * stride + j];
        outs[t] = acc;
    }
    __syncthreads();

    // ---------------- Phase E: finalize (fp32 stores) -----------------------
    if (t == 0) {
        float uu = u[n];
        float s0 = scal[2*n], s1 = scal[2*n+1];
        float tr = trans[n];
        float u_new = uu + outs[0];
        float mxn = mx + outs[1], myn = my + outs[2];
        float s0n = s0 * expf(outs[3]);
        float s1n = s1 * expf(outs[4]);
        float tn  = tr + outs[5];
        float c00 = s0n*s0n, c01 = s0n*tn, c11 = tn*tn + s1n*s1n;
        out[n]              = u_new;   // u_new         @0
        out[1024 + 2*n]     = mxn;     // means_new     @1024
        out[1024 + 2*n + 1] = myn;
        out[3072 + 2*n]     = s0n;     // scaling_new   @3072
        out[3072 + 2*n + 1] = s1n;
        out[5120 + n]       = tn;      // transform_new @5120
        out[6144 + 4*n]     = c00;     // cov_new       @6144
        out[6144 + 4*n + 1] = c01;
        out[6144 + 4*n + 2] = c01;
        out[6144 + 4*n + 3] = c11;
    }
}

// ---------------------------------------------------------------- launch
extern "C" void kernel_launch(void* const* d_in, const int* in_sizes, int n_in,
                              void* d_out, int out_size, void* d_ws, size_t ws_size,
                              hipStream_t stream)
{
    k_fused<<<dim3(NG), dim3(256), 0, stream>>>(
        (const float*)d_in[0],  (const float*)d_in[1],  (const float*)d_in[2],
        (const float*)d_in[3],  (const float*)d_in[4],  (const float*)d_in[5],
        (const float*)d_in[6],  (const float*)d_in[7],  (const float*)d_in[8],
        (const float*)d_in[9],  (const float*)d_in[10], (const float*)d_in[11],
        (const float*)d_in[12], (const float*)d_in[13], (const float*)d_in[14],
        (const float*)d_in[15], (const float*)d_in[16], (const float*)d_in[17],
        (const float*)d_in[18], (float*)d_out);
}

// Round 6
// 111.237 us; speedup vs baseline: 1.0829x; 1.0829x over previous
//
#include <hip/hip_runtime.h>
#include <hip/hip_bf16.h>

// Model_10514079940941 — fp32 in / fp32 out (verified R5, absmax 1.5e-5).
// R6: algorithmic cull. k_prep: conics + cull radius -> ws, convW transposed
// [200][75]->[75][200] -> ws. k_fused: per block, compact surviving gaussians
// (q_min > 100 culled: e <= 2e-22, contribution < 1e-13 -- invisible at 4e-2
// threshold) into LDS, then the R5-proven pairwise + MLP + finalize.

#define NG 1024
#define WS_GD   0            // 8192 floats: mx,my,A,B | C,trC,alpha*u,r2
#define WS_CWT  (NG * 8)     // 15000 floats: convW transposed [75][200]

__global__ __launch_bounds__(256) void k_prep(
    const float* __restrict__ means, const float* __restrict__ u,
    const float* __restrict__ scal,  const float* __restrict__ trans,
    const float* __restrict__ opac,  const float* __restrict__ convW,
    float* __restrict__ ws)
{
    int gid = blockIdx.x * 256 + threadIdx.x;
    if (gid < NG) {
        float gmx = means[2*gid], gmy = means[2*gid+1];
        float s0  = scal[2*gid],  s1  = scal[2*gid+1];
        float tt  = trans[gid];
        float c00 = s0*s0, c01 = s0*tt, c11 = tt*tt + s1*s1;
        float idet = 1.0f / (c00*c11 - c01*c01);
        float A = c11*idet, B = -c01*idet, C = c00*idet;
        float alpha = 1.0f / (1.0f + __expf(-opac[gid]));
        float r2 = 100.0f * (c00 + c11);   // cull: d^2 > 100*trace(cov) => q > 100
        float4* dst = (float4*)(ws + WS_GD + gid*8);
        dst[0] = make_float4(gmx, gmy, A, B);
        dst[1] = make_float4(C, A + C, alpha * u[gid], r2);
    }
    // transpose convW: [ko=200][j=75] -> [j=75][ko=200] for coalesced Phase B
    float* wt = ws + WS_CWT;
    for (int idx = gid; idx < 15000; idx += gridDim.x * 256) {
        int ko = idx / 75, j = idx - ko * 75;
        wt[j * 200 + ko] = convW[idx];
    }
}

__global__ __launch_bounds__(256) void k_fused(
    const float* __restrict__ means, const float* __restrict__ u,
    const float* __restrict__ scal, const float* __restrict__ trans,
    const float* __restrict__ opac,
    const float* __restrict__ convb,
    const float* __restrict__ embW,  const float* __restrict__ embb,
    const float* __restrict__ l1W,   const float* __restrict__ l1b,
    const float* __restrict__ oWs,  const float* __restrict__ obs,
    const float* __restrict__ oWt,  const float* __restrict__ obt,
    const float* __restrict__ oWsc, const float* __restrict__ obsc,
    const float* __restrict__ oWtf, const float* __restrict__ obtf,
    const float* __restrict__ ws,
    float* __restrict__ out)
{
    __shared__ float gcomp[NG * 8];   // 32 KB: compacted surviving gaussians
    __shared__ float pus[8][32];
    __shared__ float plap[8][32];
    __shared__ float simg[80];
    __shared__ float hin[4][80];
    __shared__ float hv[4][80];
    __shared__ float outs[8];
    __shared__ int   cnt;

    const int t = threadIdx.x;
    const int n = blockIdx.x;
    const float mx = means[2*n], my = means[2*n+1];

    // ---------------- Phase 0: cull + compact into LDS ----------------------
    if (t == 0) cnt = 0;
    __syncthreads();
    for (int g = t; g < NG; g += 256) {
        const float4* src = (const float4*)(ws + WS_GD + g*8);
        float4 a = src[0], b = src[1];
        float ddx = fmaxf(fabsf(a.x - mx) - 0.02f, 0.0f);
        float ddy = fmaxf(fabsf(a.y - my) - 0.02f, 0.0f);
        if (ddx*ddx + ddy*ddy <= b.w) {
            int slot = atomicAdd(&cnt, 1);
            float4* dst = (float4*)(gcomp + slot*8);
            dst[0] = a; dst[1] = b;
        }
    }
    __syncthreads();
    const int nsurv = cnt;

    // ---------------- Phase 1: pairwise sums over survivors, 8-way chunked --
    {
        int s = t & 31, c = t >> 5;   // wave spans 2 chunks -> 2-way alias (free)
        if (s < 25) {
            int si = s / 5, sj = s - si * 5;
            float sx = mx + (float)(si - 2) * 0.01f;
            float sy = my + (float)(sj - 2) * 0.01f;
            float us = 0.0f, lp = 0.0f;
            #pragma unroll 2
            for (int i = c; i < nsurv; i += 8) {
                float4 a = *(const float4*)(gcomp + i*8);
                float4 b = *(const float4*)(gcomp + i*8 + 4);
                float dx = sx - a.x, dy = sy - a.y;
                float Cq0 = a.z*dx + a.w*dy;
                float Cq1 = a.w*dx + b.x*dy;
                float q   = dx*Cq0 + dy*Cq1;
                float e   = __expf(-0.5f*q) * b.z;     // G * alpha * u
                us += e;
                lp += e * (Cq0*Cq0 + Cq1*Cq1 - b.y);
            }
            pus[c][s] = us; plap[c][s] = lp;
        }
    }
    __syncthreads();

    // ---------------- Phase A: reduce chunks -> img[75] ---------------------
    if (t < 25) {
        float us = 0.0f, lp = 0.0f;
        #pragma unroll
        for (int c = 0; c < 8; ++c) { us += pus[c][t]; lp += plap[c][t]; }
        int si = t / 5, sj = t - si * 5;
        float sx = mx + (float)(si - 2) * 0.01f;
        float sy = my + (float)(sj - 2) * 0.01f;
        simg[t]      = us;
        simg[25 + t] = lp;
        simg[50 + t] = (fabsf(sx) < 1.0f && fabsf(sy) < 1.0f) ? 1.0f : 0.0f;
    }
    __syncthreads();

    // ---------------- Phase B: conv (coalesced via convWT) + emb ------------
    if (t < 200) {
        const float* wt = ws + WS_CWT;
        float acc = convb[t];                  // t = k*50+o
        #pragma unroll 5
        for (int j = 0; j < 75; ++j) acc += simg[j] * wt[j*200 + t];
        hin[t / 50][t % 50] = tanhf(acc);
    } else {
        float inp[7] = { mx, my, u[n], scal[2*n], scal[2*n+1], trans[n], opac[n] };
        for (int idx = t - 200; idx < 120; idx += 56) {
            int k = idx / 30, g = idx - k * 30;
            float acc = embb[k * 30 + g];
            #pragma unroll
            for (int f = 0; f < 7; ++f) acc += inp[f] * embW[(k*7 + f)*30 + g];
            hin[k][50 + g] = tanhf(acc);
        }
    }
    __syncthreads();

    // ---------------- Phase C: l1 (coalesced already: g is inner) -----------
    for (int idx = t; idx < 320; idx += 256) {
        int k = idx / 80, g = idx - k * 80;
        float acc = l1b[k * 80 + g];
        #pragma unroll 8
        for (int f = 0; f < 80; ++f)
            acc += hin[k][f] * l1W[(k*80 + f)*80 + g];
        hv[k][g] = tanhf(acc);
    }
    __syncthreads();

    // ---------------- Phase D: output heads ---------------------------------
    if (t < 6) {
        const float* W; const float* bb; int k, j, stride;
        if (t == 0)      { W = oWs;  bb = obs;  k = 0; j = 0;     stride = 1; }
        else if (t < 3)  { W = oWt;  bb = obt;  k = 1; j = t - 1; stride = 2; }
        else if (t < 5)  { W = oWsc; bb = obsc; k = 2; j = t - 3; stride = 2; }
        else             { W = oWtf; bb = obtf; k = 3; j = 0;     stride = 1; }
        float acc = bb[j];
        #pragma unroll 8
        for (int f = 0; f < 80; ++f) acc += hv[k][f] * W[f * stride + j];
        outs[t] = acc;
    }
    __syncthreads();

    // ---------------- Phase E: finalize (fp32 stores) -----------------------
    if (t == 0) {
        float uu = u[n];
        float s0 = scal[2*n], s1 = scal[2*n+1];
        float tr = trans[n];
        float u_new = uu + outs[0];
        float mxn = mx + outs[1], myn = my + outs[2];
        float s0n = s0 * expf(outs[3]);
        float s1n = s1 * expf(outs[4]);
        float tn  = tr + outs[5];
        float c00 = s0n*s0n, c01 = s0n*tn, c11 = tn*tn + s1n*s1n;
        out[n]              = u_new;   // u_new         @0
        out[1024 + 2*n]     = mxn;     // means_new     @1024
        out[1024 + 2*n + 1] = myn;
        out[3072 + 2*n]     = s0n;     // scaling_new   @3072
        out[3072 + 2*n + 1] = s1n;
        out[5120 + n]       = tn;      // transform_new @5120
        out[6144 + 4*n]     = c00;     // cov_new       @6144
        out[6144 + 4*n + 1] = c01;
        out[6144 + 4*n + 2] = c01;
        out[6144 + 4*n + 3] = c11;
    }
}

// ---------------------------------------------------------------- launch
extern "C" void kernel_launch(void* const* d_in, const int* in_sizes, int n_in,
                              void* d_out, int out_size, void* d_ws, size_t ws_size,
                              hipStream_t stream)
{
    const float* means = (const float*)d_in[0];
    const float* u     = (const float*)d_in[1];
    const float* scal  = (const float*)d_in[2];
    const float* trans = (const float*)d_in[3];
    const float* opac  = (const float*)d_in[4];
    const float* convW = (const float*)d_in[5];
    float* ws = (float*)d_ws;

    k_prep<<<dim3(64), dim3(256), 0, stream>>>(means, u, scal, trans, opac,
                                               convW, ws);
    k_fused<<<dim3(NG), dim3(256), 0, stream>>>(
        means, u, scal, trans, opac,
        (const float*)d_in[6],  (const float*)d_in[7],  (const float*)d_in[8],
        (const float*)d_in[9],  (const float*)d_in[10], (const float*)d_in[11],
        (const float*)d_in[12], (const float*)d_in[13], (const float*)d_in[14],
        (const float*)d_in[15], (const float*)d_in[16], (const float*)d_in[17],
        (const float*)d_in[18], ws, (float*)d_out);
}

// Round 7
// 108.733 us; speedup vs baseline: 1.1078x; 1.0230x over previous
//
#include <hip/hip_runtime.h>
#include <hip/hip_bf16.h>

// Model_10514079940941 — fp32 in / fp32 out (verified R5/R6).
// R7: batch 2 gaussians per block (512 blocks): halves weight traffic +
// barriers, conv/l1 weights loaded once and reused for both gaussians.
// Fast tanh via hardware v_exp_f32. Cull (verified R6): q>100 culled,
// contribution < 1e-13, invisible at 4.4e-2 threshold.

#define NG 1024
#define WS_GD   0            // 8192 floats: mx,my,A,B | C,trC,alpha*u,r2
#define WS_CWT  (NG * 8)     // 15000 floats: convW transposed [75][200]

__device__ __forceinline__ float tanh_fast(float x) {
    // 1 - 2/(e^{2x}+1): saturates correctly both ways, ~1e-6 rel err
    return 1.0f - 2.0f / (__expf(2.0f * x) + 1.0f);
}

__global__ __launch_bounds__(256) void k_prep(
    const float* __restrict__ means, const float* __restrict__ u,
    const float* __restrict__ scal,  const float* __restrict__ trans,
    const float* __restrict__ opac,  const float* __restrict__ convW,
    float* __restrict__ ws)
{
    int gid = blockIdx.x * 256 + threadIdx.x;
    if (gid < NG) {
        float gmx = means[2*gid], gmy = means[2*gid+1];
        float s0  = scal[2*gid],  s1  = scal[2*gid+1];
        float tt  = trans[gid];
        float c00 = s0*s0, c01 = s0*tt, c11 = tt*tt + s1*s1;
        float idet = 1.0f / (c00*c11 - c01*c01);
        float A = c11*idet, B = -c01*idet, C = c00*idet;
        float alpha = 1.0f / (1.0f + __expf(-opac[gid]));
        float r2 = 100.0f * (c00 + c11);   // d^2 > 100*trace(cov) => q > 100
        float4* dst = (float4*)(ws + WS_GD + gid*8);
        dst[0] = make_float4(gmx, gmy, A, B);
        dst[1] = make_float4(C, A + C, alpha * u[gid], r2);
    }
    float* wt = ws + WS_CWT;  // convW [200][75] -> [75][200]
    for (int idx = gid; idx < 15000; idx += gridDim.x * 256) {
        int ko = idx / 75, j = idx - ko * 75;
        wt[j * 200 + ko] = convW[idx];
    }
}

__global__ __launch_bounds__(256) void k_fused(
    const float* __restrict__ means, const float* __restrict__ u,
    const float* __restrict__ scal, const float* __restrict__ trans,
    const float* __restrict__ opac,
    const float* __restrict__ convb,
    const float* __restrict__ embW,  const float* __restrict__ embb,
    const float* __restrict__ l1W,   const float* __restrict__ l1b,
    const float* __restrict__ oWs,  const float* __restrict__ obs,
    const float* __restrict__ oWt,  const float* __restrict__ obt,
    const float* __restrict__ oWsc, const float* __restrict__ obsc,
    const float* __restrict__ oWtf, const float* __restrict__ obtf,
    const float* __restrict__ ws,
    float* __restrict__ out)
{
    __shared__ float gcomp[NG * 8];   // 32 KB worst case (all survive)
    __shared__ float pus[2][4][32];
    __shared__ float plap[2][4][32];
    __shared__ float simg[2][80];
    __shared__ float hin[2][4][80];
    __shared__ float hv[2][4][80];
    __shared__ float outs[2][8];
    __shared__ int   cnt;

    const int t  = threadIdx.x;
    const int n0 = blockIdx.x * 2;
    const float mx0 = means[2*n0],   my0 = means[2*n0+1];
    const float mx1 = means[2*n0+2], my1 = means[2*n0+3];
    // sample bounding box for both gaussians (+/-0.02 kernel extent)
    const float bxmin = fminf(mx0, mx1) - 0.02f, bxmax = fmaxf(mx0, mx1) + 0.02f;
    const float bymin = fminf(my0, my1) - 0.02f, bymax = fmaxf(my0, my1) + 0.02f;

    // ---------------- Phase 0: cull vs box + compact into LDS ---------------
    if (t == 0) cnt = 0;
    __syncthreads();
    for (int g = t; g < NG; g += 256) {
        const float4* src = (const float4*)(ws + WS_GD + g*8);
        float4 a = src[0], b = src[1];
        float ddx = fmaxf(fmaxf(bxmin - a.x, a.x - bxmax), 0.0f);
        float ddy = fmaxf(fmaxf(bymin - a.y, a.y - bymax), 0.0f);
        if (ddx*ddx + ddy*ddy <= b.w) {
            int slot = atomicAdd(&cnt, 1);
            float4* dst = (float4*)(gcomp + slot*8);
            dst[0] = a; dst[1] = b;
        }
    }
    __syncthreads();
    const int nsurv = cnt;

    // ---------------- Phase 1: pairwise sums ---------------------------------
    // t = c*64 + l*32 + s : chunk c in [0,4), gaussian l in {0,1}, sample s<25.
    // All 64 lanes of a wave read the same gcomp entry -> broadcast (free).
    {
        int c = t >> 6, lane = t & 63, l = lane >> 5, s = lane & 31;
        if (s < 25) {
            int si = s / 5, sj = s - si * 5;
            float gx = l ? mx1 : mx0, gy = l ? my1 : my0;
            float sx = gx + (float)(si - 2) * 0.01f;
            float sy = gy + (float)(sj - 2) * 0.01f;
            float us = 0.0f, lp = 0.0f;
            #pragma unroll 2
            for (int i = c; i < nsurv; i += 4) {
                float4 a = *(const float4*)(gcomp + i*8);
                float4 b = *(const float4*)(gcomp + i*8 + 4);
                float dx = sx - a.x, dy = sy - a.y;
                float Cq0 = a.z*dx + a.w*dy;
                float Cq1 = a.w*dx + b.x*dy;
                float q   = dx*Cq0 + dy*Cq1;
                float e   = __expf(-0.5f*q) * b.z;     // G * alpha * u
                us += e;
                lp += e * (Cq0*Cq0 + Cq1*Cq1 - b.y);
            }
            pus[l][c][s] = us; plap[l][c][s] = lp;
        }
    }
    __syncthreads();

    // ---------------- Phase A: reduce chunks -> img[2][75] -------------------
    if (t < 50) {
        int l = t / 25, s = t - l * 25;
        float us = 0.0f, lp = 0.0f;
        #pragma unroll
        for (int c = 0; c < 4; ++c) { us += pus[l][c][s]; lp += plap[l][c][s]; }
        int si = s / 5, sj = s - si * 5;
        float gx = l ? mx1 : mx0, gy = l ? my1 : my0;
        float sx = gx + (float)(si - 2) * 0.01f;
        float sy = gy + (float)(sj - 2) * 0.01f;
        simg[l][s]      = us;
        simg[l][25 + s] = lp;
        simg[l][50 + s] = (fabsf(sx) < 1.0f && fabsf(sy) < 1.0f) ? 1.0f : 0.0f;
    }
    __syncthreads();

    // ---------------- Phase B: conv (weight reused x2) + emb -----------------
    if (t < 200) {
        const float* wt = ws + WS_CWT;
        float a0 = convb[t], a1 = a0;          // t = k*50+o
        #pragma unroll 5
        for (int j = 0; j < 75; ++j) {
            float w = wt[j*200 + t];
            a0 += simg[0][j] * w;
            a1 += simg[1][j] * w;
        }
        int k = t / 50, o = t - k * 50;
        hin[0][k][o] = tanh_fast(a0);
        hin[1][k][o] = tanh_fast(a1);
    } else {
        for (int idx = t - 200; idx < 240; idx += 56) {
            int l = idx / 120, rem = idx - l * 120;
            int k = rem / 30, g = rem - k * 30;
            int n = n0 + l;
            float inp[7] = { means[2*n], means[2*n+1], u[n], scal[2*n],
                             scal[2*n+1], trans[n], opac[n] };
            float acc = embb[k * 30 + g];
            #pragma unroll
            for (int f = 0; f < 7; ++f) acc += inp[f] * embW[(k*7 + f)*30 + g];
            hin[l][k][50 + g] = tanh_fast(acc);
        }
    }
    __syncthreads();

    // ---------------- Phase C: l1, weight reused x2 --------------------------
    for (int p = t; p < 320; p += 256) {
        int k = p / 80, g = p - k * 80;
        float a0 = l1b[p], a1 = a0;
        #pragma unroll 8
        for (int f = 0; f < 80; ++f) {
            float w = l1W[(k*80 + f)*80 + g];
            a0 += hin[0][k][f] * w;
            a1 += hin[1][k][f] * w;
        }
        hv[0][k][g] = tanh_fast(a0);
        hv[1][k][g] = tanh_fast(a1);
    }
    __syncthreads();

    // ---------------- Phase D: output heads (2 x 6 dots of 80) ---------------
    if (t < 12) {
        int l = t / 6, t6 = t - l * 6;
        const float* W; const float* bb; int k, j, stride;
        if (t6 == 0)      { W = oWs;  bb = obs;  k = 0; j = 0;      stride = 1; }
        else if (t6 < 3)  { W = oWt;  bb = obt;  k = 1; j = t6 - 1; stride = 2; }
        else if (t6 < 5)  { W = oWsc; bb = obsc; k = 2; j = t6 - 3; stride = 2; }
        else              { W = oWtf; bb = obtf; k = 3; j = 0;      stride = 1; }
        float acc = bb[j];
        #pragma unroll 8
        for (int f = 0; f < 80; ++f) acc += hv[l][k][f] * W[f * stride + j];
        outs[l][t6] = acc;
    }
    __syncthreads();

    // ---------------- Phase E: finalize (fp32 stores) ------------------------
    if (t < 2) {
        int n = n0 + t;
        float uu = u[n];
        float s0 = scal[2*n], s1 = scal[2*n+1];
        float tr = trans[n];
        float u_new = uu + outs[t][0];
        float mxn = (t ? mx1 : mx0) + outs[t][1];
        float myn = (t ? my1 : my0) + outs[t][2];
        float s0n = s0 * __expf(outs[t][3]);
        float s1n = s1 * __expf(outs[t][4]);
        float tn  = tr + outs[t][5];
        float c00 = s0n*s0n, c01 = s0n*tn, c11 = tn*tn + s1n*s1n;
        out[n]              = u_new;   // u_new         @0
        out[1024 + 2*n]     = mxn;     // means_new     @1024
        out[1024 + 2*n + 1] = myn;
        out[3072 + 2*n]     = s0n;     // scaling_new   @3072
        out[3072 + 2*n + 1] = s1n;
        out[5120 + n]       = tn;      // transform_new @5120
        out[6144 + 4*n]     = c00;     // cov_new       @6144
        out[6144 + 4*n + 1] = c01;
        out[6144 + 4*n + 2] = c01;
        out[6144 + 4*n + 3] = c11;
    }
}

// ---------------------------------------------------------------- launch
extern "C" void kernel_launch(void* const* d_in, const int* in_sizes, int n_in,
                              void* d_out, int out_size, void* d_ws, size_t ws_size,
                              hipStream_t stream)
{
    const float* means = (const float*)d_in[0];
    const float* u     = (const float*)d_in[1];
    const float* scal  = (const float*)d_in[2];
    const float* trans = (const float*)d_in[3];
    const float* opac  = (const float*)d_in[4];
    const float* convW = (const float*)d_in[5];
    float* ws = (float*)d_ws;

    k_prep<<<dim3(64), dim3(256), 0, stream>>>(means, u, scal, trans, opac,
                                               convW, ws);
    k_fused<<<dim3(NG / 2), dim3(256), 0, stream>>>(
        means, u, scal, trans, opac,
        (const float*)d_in[6],  (const float*)d_in[7],  (const float*)d_in[8],
        (const float*)d_in[9],  (const float*)d_in[10], (const float*)d_in[11],
        (const float*)d_in[12], (const float*)d_in[13], (const float*)d_in[14],
        (const float*)d_in[15], (const float*)d_in[16], (const float*)d_in[17],
        (const float*)d_in[18], ws, (float*)d_out);
}

// Round 8
// 108.030 us; speedup vs baseline: 1.1150x; 1.0065x over previous
//
#include <hip/hip_runtime.h>
#include <hip/hip_bf16.h>

// Model_10514079940941 — fp32 in / fp32 out (verified R5-R7).
// R8: SINGLE kernel, zero workspace traffic. Cull from raw inputs
// (r2 = 100*trace(cov); q>100 => contribution < 1e-13, invisible at 4.4e-2
// threshold — verified R6/R7). Conic computed only for survivors, in LDS.
// 2 gaussians per block (512 blocks), weights streamed once per block and
// reused for both. Fast tanh via v_exp_f32 (verified R7).

#define NG 1024

__device__ __forceinline__ float tanh_fast(float x) {
    return 1.0f - 2.0f / (__expf(2.0f * x) + 1.0f);
}

__global__ __launch_bounds__(256) void k_fused(
    const float* __restrict__ means, const float* __restrict__ u,
    const float* __restrict__ scal, const float* __restrict__ trans,
    const float* __restrict__ opac,
    const float* __restrict__ convW, const float* __restrict__ convb,
    const float* __restrict__ embW,  const float* __restrict__ embb,
    const float* __restrict__ l1W,   const float* __restrict__ l1b,
    const float* __restrict__ oWs,  const float* __restrict__ obs,
    const float* __restrict__ oWt,  const float* __restrict__ obt,
    const float* __restrict__ oWsc, const float* __restrict__ obsc,
    const float* __restrict__ oWtf, const float* __restrict__ obtf,
    float* __restrict__ out)
{
    __shared__ float gcomp[NG * 8];   // worst case all survive: 32 KB
    __shared__ float pus[2][4][32];
    __shared__ float plap[2][4][32];
    __shared__ float simg[2][80];
    __shared__ float hin[2][4][80];
    __shared__ float hv[2][4][80];
    __shared__ float outs[2][8];
    __shared__ int   cnt;

    const int t  = threadIdx.x;
    const int n0 = blockIdx.x * 2;
    const float mx0 = means[2*n0],   my0 = means[2*n0+1];
    const float mx1 = means[2*n0+2], my1 = means[2*n0+3];
    const float bxmin = fminf(mx0, mx1) - 0.02f, bxmax = fmaxf(mx0, mx1) + 0.02f;
    const float bymin = fminf(my0, my1) - 0.02f, bymax = fmaxf(my0, my1) + 0.02f;

    // ---- Phase 0: cull from raw inputs; conic only for survivors -----------
    if (t == 0) cnt = 0;
    __syncthreads();
    for (int g = t; g < NG; g += 256) {           // 4 iterations
        float gmx = means[2*g], gmy = means[2*g+1];
        float s0  = scal[2*g],  s1  = scal[2*g+1];
        float tt  = trans[g];
        float c00 = s0*s0, c01 = s0*tt, c11 = tt*tt + s1*s1;
        float r2  = 100.0f * (c00 + c11);          // q>100 culled
        float ddx = fmaxf(fmaxf(bxmin - gmx, gmx - bxmax), 0.0f);
        float ddy = fmaxf(fmaxf(bymin - gmy, gmy - bymax), 0.0f);
        if (ddx*ddx + ddy*ddy <= r2) {             // ~30/1024 lanes survive
            float idet = 1.0f / (c00*c11 - c01*c01);
            float A = c11*idet, B = -c01*idet, C = c00*idet;
            float alpha = 1.0f / (1.0f + __expf(-opac[g]));
            int slot = atomicAdd(&cnt, 1);
            float4* dst = (float4*)(gcomp + slot*8);
            dst[0] = make_float4(gmx, gmy, A, B);
            dst[1] = make_float4(C, A + C, alpha * u[g], 0.0f);
        }
    }
    __syncthreads();
    const int nsurv = cnt;

    // ---- Phase 1: pairwise sums. t = c*64 + l*32 + s ------------------------
    {
        int c = t >> 6, lane = t & 63, l = lane >> 5, s = lane & 31;
        if (s < 25) {
            int si = s / 5, sj = s - si * 5;
            float gx = l ? mx1 : mx0, gy = l ? my1 : my0;
            float sx = gx + (float)(si - 2) * 0.01f;
            float sy = gy + (float)(sj - 2) * 0.01f;
            float us = 0.0f, lp = 0.0f;
            #pragma unroll 2
            for (int i = c; i < nsurv; i += 4) {
                float4 a = *(const float4*)(gcomp + i*8);
                float4 b = *(const float4*)(gcomp + i*8 + 4);
                float dx = sx - a.x, dy = sy - a.y;
                float Cq0 = a.z*dx + a.w*dy;
                float Cq1 = a.w*dx + b.x*dy;
                float q   = dx*Cq0 + dy*Cq1;
                float e   = __expf(-0.5f*q) * b.z;     // G * alpha * u
                us += e;
                lp += e * (Cq0*Cq0 + Cq1*Cq1 - b.y);
            }
            pus[l][c][s] = us; plap[l][c][s] = lp;
        }
    }
    __syncthreads();

    // ---- Phase A: reduce chunks -> img[2][75] -------------------------------
    if (t < 50) {
        int l = t / 25, s = t - l * 25;
        float us = 0.0f, lp = 0.0f;
        #pragma unroll
        for (int c = 0; c < 4; ++c) { us += pus[l][c][s]; lp += plap[l][c][s]; }
        int si = s / 5, sj = s - si * 5;
        float gx = l ? mx1 : mx0, gy = l ? my1 : my0;
        float sx = gx + (float)(si - 2) * 0.01f;
        float sy = gy + (float)(sj - 2) * 0.01f;
        simg[l][s]      = us;
        simg[l][25 + s] = lp;
        simg[l][50 + s] = (fabsf(sx) < 1.0f && fabsf(sy) < 1.0f) ? 1.0f : 0.0f;
    }
    __syncthreads();

    // ---- Phase B: conv (row-major dot, weights reused x2) + emb -------------
    if (t < 200) {
        const float* w = convW + (size_t)t * 75;   // t = k*50+o
        float a0 = convb[t], a1 = a0;
        #pragma unroll 5
        for (int j = 0; j < 75; ++j) {
            float wj = w[j];
            a0 += simg[0][j] * wj;
            a1 += simg[1][j] * wj;
        }
        int k = t / 50, o = t - k * 50;
        hin[0][k][o] = tanh_fast(a0);
        hin[1][k][o] = tanh_fast(a1);
    } else {
        for (int idx = t - 200; idx < 240; idx += 56) {
            int l = idx / 120, rem = idx - l * 120;
            int k = rem / 30, g = rem - k * 30;
            int n = n0 + l;
            float inp[7] = { means[2*n], means[2*n+1], u[n], scal[2*n],
                             scal[2*n+1], trans[n], opac[n] };
            float acc = embb[k * 30 + g];
            #pragma unroll
            for (int f = 0; f < 7; ++f) acc += inp[f] * embW[(k*7 + f)*30 + g];
            hin[l][k][50 + g] = tanh_fast(acc);
        }
    }
    __syncthreads();

    // ---- Phase C: l1 (g-coalesced), weights reused x2 -----------------------
    for (int p = t; p < 320; p += 256) {
        int k = p / 80, g = p - k * 80;
        float a0 = l1b[p], a1 = a0;
        #pragma unroll 8
        for (int f = 0; f < 80; ++f) {
            float w = l1W[(k*80 + f)*80 + g];
            a0 += hin[0][k][f] * w;
            a1 += hin[1][k][f] * w;
        }
        hv[0][k][g] = tanh_fast(a0);
        hv[1][k][g] = tanh_fast(a1);
    }
    __syncthreads();

    // ---- Phase D: output heads (2 x 6 dots of 80) ---------------------------
    if (t < 12) {
        int l = t / 6, t6 = t - l * 6;
        const float* W; const float* bb; int k, j, stride;
        if (t6 == 0)      { W = oWs;  bb = obs;  k = 0; j = 0;      stride = 1; }
        else if (t6 < 3)  { W = oWt;  bb = obt;  k = 1; j = t6 - 1; stride = 2; }
        else if (t6 < 5)  { W = oWsc; bb = obsc; k = 2; j = t6 - 3; stride = 2; }
        else              { W = oWtf; bb = obtf; k = 3; j = 0;      stride = 1; }
        float acc = bb[j];
        #pragma unroll 8
        for (int f = 0; f < 80; ++f) acc += hv[l][k][f] * W[f * stride + j];
        outs[l][t6] = acc;
    }
    __syncthreads();

    // ---- Phase E: finalize (fp32 stores) ------------------------------------
    if (t < 2) {
        int n = n0 + t;
        float uu = u[n];
        float s0 = scal[2*n], s1 = scal[2*n+1];
        float tr = trans[n];
        float u_new = uu + outs[t][0];
        float mxn = (t ? mx1 : mx0) + outs[t][1];
        float myn = (t ? my1 : my0) + outs[t][2];
        float s0n = s0 * __expf(outs[t][3]);
        float s1n = s1 * __expf(outs[t][4]);
        float tn  = tr + outs[t][5];
        float c00 = s0n*s0n, c01 = s0n*tn, c11 = tn*tn + s1n*s1n;
        out[n]              = u_new;   // u_new         @0
        out[1024 + 2*n]     = mxn;     // means_new     @1024
        out[1024 + 2*n + 1] = myn;
        out[3072 + 2*n]     = s0n;     // scaling_new   @3072
        out[3072 + 2*n + 1] = s1n;
        out[5120 + n]       = tn;      // transform_new @5120
        out[6144 + 4*n]     = c00;     // cov_new       @6144
        out[6144 + 4*n + 1] = c01;
        out[6144 + 4*n + 2] = c01;
        out[6144 + 4*n + 3] = c11;
    }
}

// ---------------------------------------------------------------- launch
extern "C" void kernel_launch(void* const* d_in, const int* in_sizes, int n_in,
                              void* d_out, int out_size, void* d_ws, size_t ws_size,
                              hipStream_t stream)
{
    k_fused<<<dim3(NG / 2), dim3(256), 0, stream>>>(
        (const float*)d_in[0],  (const float*)d_in[1],  (const float*)d_in[2],
        (const float*)d_in[3],  (const float*)d_in[4],  (const float*)d_in[5],
        (const float*)d_in[6],  (const float*)d_in[7],  (const float*)d_in[8],
        (const float*)d_in[9],  (const float*)d_in[10], (const float*)d_in[11],
        (const float*)d_in[12], (const float*)d_in[13], (const float*)d_in[14],
        (const float*)d_in[15], (const float*)d_in[16], (const float*)d_in[17],
        (const float*)d_in[18], (float*)d_out);
}

// Round 9
// 106.386 us; speedup vs baseline: 1.1323x; 1.0155x over previous
//
#include <hip/hip_runtime.h>
#include <hip/hip_bf16.h>

// Model_10514079940941 — fp32 in / fp32 out (verified R5-R8).
// R9: latency-chain attack. Conv+l1 weights prefetched into REGISTERS at
// kernel start (independent loads overlap Phase 0/1 entirely); Phase-1 chunk
// reduce via in-wave shfl; Phase D+E fused in wave 0 via shfl (no barrier).
// Cull (verified R6-R8): q>100 => contribution < 1e-13, invisible at 4.4e-2.
// 2 gaussians/block, 512 blocks, all co-resident.

#define NG 1024

__device__ __forceinline__ float tanh_fast(float x) {
    return 1.0f - 2.0f / (__expf(2.0f * x) + 1.0f);
}

__global__ __launch_bounds__(256) void k_fused(
    const float* __restrict__ means, const float* __restrict__ u,
    const float* __restrict__ scal, const float* __restrict__ trans,
    const float* __restrict__ opac,
    const float* __restrict__ convW, const float* __restrict__ convb,
    const float* __restrict__ embW,  const float* __restrict__ embb,
    const float* __restrict__ l1W,   const float* __restrict__ l1b,
    const float* __restrict__ oWs,  const float* __restrict__ obs,
    const float* __restrict__ oWt,  const float* __restrict__ obt,
    const float* __restrict__ oWsc, const float* __restrict__ obsc,
    const float* __restrict__ oWtf, const float* __restrict__ obtf,
    float* __restrict__ out)
{
    __shared__ float gcomp[NG * 8];   // worst case all survive: 32 KB
    __shared__ float pus[2][2][32];
    __shared__ float plap[2][2][32];
    __shared__ float simg[2][80];
    __shared__ float hin[2][4][80];
    __shared__ float hv[2][4][80];
    __shared__ int   cnt;

    const int t  = threadIdx.x;
    const int n0 = blockIdx.x * 2;

    // ---- register prefetch of weights: independent of ALL phases ----------
    // conv row for output t (t<200 meaningful): 75 floats
    float wcv[75];
    {
        const float* w = convW + (size_t)(t < 200 ? t : 0) * 75;
        #pragma unroll
        for (int j = 0; j < 75; ++j) wcv[j] = w[j];
    }
    // l1 row for output t (outputs 0..255): k=t/80, g=t%80, stride-80 over f
    float w1[80];
    {
        int k = t / 80, g = t - (t / 80) * 80;
        const float* w = l1W + (size_t)(k * 80) * 80 + g;
        #pragma unroll
        for (int f = 0; f < 80; ++f) w1[f] = w[f * 80];
    }
    float bcv = (t < 200) ? convb[t] : 0.0f;
    float b1  = l1b[t];

    const float mx0 = means[2*n0],   my0 = means[2*n0+1];
    const float mx1 = means[2*n0+2], my1 = means[2*n0+3];
    const float bxmin = fminf(mx0, mx1) - 0.02f, bxmax = fmaxf(mx0, mx1) + 0.02f;
    const float bymin = fminf(my0, my1) - 0.02f, bymax = fmaxf(my0, my1) + 0.02f;

    // ---- Phase 0: cull from raw inputs; conic only for survivors -----------
    if (t == 0) cnt = 0;
    __syncthreads();
    for (int g = t; g < NG; g += 256) {
        float gmx = means[2*g], gmy = means[2*g+1];
        float s0  = scal[2*g],  s1  = scal[2*g+1];
        float tt  = trans[g];
        float c00 = s0*s0, c01 = s0*tt, c11 = tt*tt + s1*s1;
        float r2  = 100.0f * (c00 + c11);          // q>100 culled
        float ddx = fmaxf(fmaxf(bxmin - gmx, gmx - bxmax), 0.0f);
        float ddy = fmaxf(fmaxf(bymin - gmy, gmy - bymax), 0.0f);
        if (ddx*ddx + ddy*ddy <= r2) {
            float idet = 1.0f / (c00*c11 - c01*c01);
            float A = c11*idet, B = -c01*idet, C = c00*idet;
            float alpha = 1.0f / (1.0f + __expf(-opac[g]));
            int slot = atomicAdd(&cnt, 1);
            float4* dst = (float4*)(gcomp + slot*8);
            dst[0] = make_float4(gmx, gmy, A, B);
            dst[1] = make_float4(C, A + C, alpha * u[g], 0.0f);
        }
    }
    __syncthreads();
    const int nsurv = cnt;

    // ---- Phase 1: pairwise. wave w: gaussian l=w>>1; chunk=(w&1)*2+lanehalf.
    {
        int w = t >> 6, lane = t & 63;
        int l = w >> 1;
        int hc = ((w & 1) << 1) | (lane >> 5);
        int s  = lane & 31; if (s > 24) s = 24;     // lanes 25-31 redundant
        int si = s / 5, sj = s - si * 5;
        float gx = l ? mx1 : mx0, gy = l ? my1 : my0;
        float sx = gx + (float)(si - 2) * 0.01f;
        float sy = gy + (float)(sj - 2) * 0.01f;
        float us = 0.0f, lp = 0.0f;
        #pragma unroll 2
        for (int i = hc; i < nsurv; i += 4) {
            float4 a = *(const float4*)(gcomp + i*8);
            float4 b = *(const float4*)(gcomp + i*8 + 4);
            float dx = sx - a.x, dy = sy - a.y;
            float Cq0 = a.z*dx + a.w*dy;
            float Cq1 = a.w*dx + b.x*dy;
            float q   = dx*Cq0 + dy*Cq1;
            float e   = __expf(-0.5f*q) * b.z;     // G * alpha * u
            us += e;
            lp += e * (Cq0*Cq0 + Cq1*Cq1 - b.y);
        }
        us += __shfl_down(us, 32);                 // combine lane-half chunks
        lp += __shfl_down(lp, 32);
        if ((lane & 31) == s && lane < 32) {       // lanes 0..24 only
            pus[l][w & 1][s] = us; plap[l][w & 1][s] = lp;
        }
    }
    __syncthreads();

    // ---- Phase A: combine 2 wave-partials -> img[2][75] ---------------------
    if (t < 50) {
        int l = t / 25, s = t - l * 25;
        float us = pus[l][0][s] + pus[l][1][s];
        float lp = plap[l][0][s] + plap[l][1][s];
        int si = s / 5, sj = s - si * 5;
        float gx = l ? mx1 : mx0, gy = l ? my1 : my0;
        float sx = gx + (float)(si - 2) * 0.01f;
        float sy = gy + (float)(sj - 2) * 0.01f;
        simg[l][s]      = us;
        simg[l][25 + s] = lp;
        simg[l][50 + s] = (fabsf(sx) < 1.0f && fabsf(sy) < 1.0f) ? 1.0f : 0.0f;
    }
    __syncthreads();

    // ---- Phase B: conv from REGISTERS (x2 gaussians) + emb ------------------
    if (t < 200) {
        float a0 = bcv, a1 = bcv;
        #pragma unroll
        for (int j = 0; j < 75; ++j) {
            a0 += simg[0][j] * wcv[j];
            a1 += simg[1][j] * wcv[j];
        }
        int k = t / 50, o = t - k * 50;
        hin[0][k][o] = tanh_fast(a0);
        hin[1][k][o] = tanh_fast(a1);
    } else {
        for (int idx = t - 200; idx < 240; idx += 56) {
            int l = idx / 120, rem = idx - l * 120;
            int k = rem / 30, g = rem - k * 30;
            int n = n0 + l;
            float inp[7] = { means[2*n], means[2*n+1], u[n], scal[2*n],
                             scal[2*n+1], trans[n], opac[n] };
            float acc = embb[k * 30 + g];
            #pragma unroll
            for (int f = 0; f < 7; ++f) acc += inp[f] * embW[(k*7 + f)*30 + g];
            hin[l][k][50 + g] = tanh_fast(acc);
        }
    }
    __syncthreads();

    // ---- Phase C: l1. Outputs 0..255 from registers; 256..319 from L2 -------
    {
        int k = t / 80, g = t - (t / 80) * 80;
        float a0 = b1, a1 = b1;
        #pragma unroll
        for (int f = 0; f < 80; ++f) {
            a0 += hin[0][k][f] * w1[f];
            a1 += hin[1][k][f] * w1[f];
        }
        hv[0][k][g] = tanh_fast(a0);
        hv[1][k][g] = tanh_fast(a1);
    }
    if (t < 64) {                                   // outputs 256..319: k=3
        int g = 16 + t;
        float a0 = l1b[240 + g], a1 = a0;
        #pragma unroll 8
        for (int f = 0; f < 80; ++f) {
            float w = l1W[(3*80 + f)*80 + g];
            a0 += hin[0][3][f] * w;
            a1 += hin[1][3][f] * w;
        }
        hv[0][3][g] = tanh_fast(a0);
        hv[1][3][g] = tanh_fast(a1);
    }
    __syncthreads();

    // ---- Phase D+E: heads + finalize, wave 0 only, shfl gather --------------
    if (t < 64) {
        int l = (t / 6) & 1, t6 = t % 6;            // lanes 12-63 redundant
        const float* W; const float* bb; int k, j, stride;
        if (t6 == 0)      { W = oWs;  bb = obs;  k = 0; j = 0;      stride = 1; }
        else if (t6 < 3)  { W = oWt;  bb = obt;  k = 1; j = t6 - 1; stride = 2; }
        else if (t6 < 5)  { W = oWsc; bb = obsc; k = 2; j = t6 - 3; stride = 2; }
        else              { W = oWtf; bb = obtf; k = 3; j = 0;      stride = 1; }
        float acc = bb[j];
        #pragma unroll 8
        for (int f = 0; f < 80; ++f) acc += hv[l][k][f] * W[f * stride + j];

        int base = (t / 6) * 6;                     // lane 0 -> 0, lane 6 -> 6
        float o0 = __shfl(acc, base + 0);
        float o1 = __shfl(acc, base + 1);
        float o2 = __shfl(acc, base + 2);
        float o3 = __shfl(acc, base + 3);
        float o4 = __shfl(acc, base + 4);
        float o5 = __shfl(acc, base + 5);

        if (t == 0 || t == 6) {
            int n = n0 + (t / 6);
            float uu = u[n];
            float s0 = scal[2*n], s1 = scal[2*n+1];
            float tr = trans[n];
            float u_new = uu + o0;
            float mxn = (t ? mx1 : mx0) + o1;
            float myn = (t ? my1 : my0) + o2;
            float s0n = s0 * __expf(o3);
            float s1n = s1 * __expf(o4);
            float tn  = tr + o5;
            float c00 = s0n*s0n, c01 = s0n*tn, c11 = tn*tn + s1n*s1n;
            out[n]              = u_new;   // u_new         @0
            out[1024 + 2*n]     = mxn;     // means_new     @1024
            out[1024 + 2*n + 1] = myn;
            out[3072 + 2*n]     = s0n;     // scaling_new   @3072
            out[3072 + 2*n + 1] = s1n;
            out[5120 + n]       = tn;      // transform_new @5120
            out[6144 + 4*n]     = c00;     // cov_new       @6144
            out[6144 + 4*n + 1] = c01;
            out[6144 + 4*n + 2] = c01;
            out[6144 + 4*n + 3] = c11;
        }
    }
}

// ---------------------------------------------------------------- launch
extern "C" void kernel_launch(void* const* d_in, const int* in_sizes, int n_in,
                              void* d_out, int out_size, void* d_ws, size_t ws_size,
                              hipStream_t stream)
{
    k_fused<<<dim3(NG / 2), dim3(256), 0, stream>>>(
        (const float*)d_in[0],  (const float*)d_in[1],  (const float*)d_in[2],
        (const float*)d_in[3],  (const float*)d_in[4],  (const float*)d_in[5],
        (const float*)d_in[6],  (const float*)d_in[7],  (const float*)d_in[8],
        (const float*)d_in[9],  (const float*)d_in[10], (const float*)d_in[11],
        (const float*)d_in[12], (const float*)d_in[13], (const float*)d_in[14],
        (const float*)d_in[15], (const float*)d_in[16], (const float*)d_in[17],
        (const float*)d_in[18], (float*)d_out);
}

// Round 10
// 104.965 us; speedup vs baseline: 1.1476x; 1.0135x over previous
//
#include <hip/hip_runtime.h>
#include <hip/hip_bf16.h>

// Model_10514079940941 — fp32 in / fp32 out (verified R5-R9).
// R10: all small weights (embW/embb/head W+b) LDS-prefetched at kernel start;
// per-block scalar inputs preloaded as uniform s-loads. After each barrier the
// critical path is pure VALU/LDS — no cold global loads left on the chain.
// Cull (verified R6-R9): q>100 => contribution < 1e-13 at 4.4e-2 threshold.
// 2 gaussians/block, 512 blocks; conv+l1 weights in registers (R9).

#define NG 1024

__device__ __forceinline__ float tanh_fast(float x) {
    return 1.0f - 2.0f / (__expf(2.0f * x) + 1.0f);
}

__global__ __launch_bounds__(256) void k_fused(
    const float* __restrict__ means, const float* __restrict__ u,
    const float* __restrict__ scal, const float* __restrict__ trans,
    const float* __restrict__ opac,
    const float* __restrict__ convW, const float* __restrict__ convb,
    const float* __restrict__ embW,  const float* __restrict__ embb,
    const float* __restrict__ l1W,   const float* __restrict__ l1b,
    const float* __restrict__ oWs,  const float* __restrict__ obs,
    const float* __restrict__ oWt,  const float* __restrict__ obt,
    const float* __restrict__ oWsc, const float* __restrict__ obsc,
    const float* __restrict__ oWtf, const float* __restrict__ obtf,
    float* __restrict__ out)
{
    __shared__ float gcomp[NG * 8];   // worst case all survive: 32 KB
    __shared__ float pus[2][2][32];
    __shared__ float plap[2][2][32];
    __shared__ float simg[2][80];
    __shared__ float hin[2][4][80];
    __shared__ float hv[2][4][80];
    __shared__ float semb[840];       // embW copy
    __shared__ float sembb[120];
    __shared__ float shead[480];      // oWs(80)|oWt(160)|oWsc(160)|oWtf(80)
    __shared__ float sheadb[6];
    __shared__ int   cnt;

    const int t  = threadIdx.x;
    const int n0 = blockIdx.x * 2;

    // ---- wave-uniform scalar preloads (s-loads, in flight from cycle 0) ----
    const float mx0 = means[2*n0],   my0 = means[2*n0+1];
    const float mx1 = means[2*n0+2], my1 = means[2*n0+3];
    const float uu0 = u[n0],     uu1 = u[n0+1];
    const float sc00 = scal[2*n0],   sc01 = scal[2*n0+1];
    const float sc10 = scal[2*n0+2], sc11 = scal[2*n0+3];
    const float tr0 = trans[n0], tr1 = trans[n0+1];
    const float op0 = opac[n0],  op1 = opac[n0+1];

    // ---- register prefetch of conv/l1 weights (independent of all phases) --
    float wcv[75];
    {
        const float* w = convW + (size_t)(t < 200 ? t : 0) * 75;
        #pragma unroll
        for (int j = 0; j < 75; ++j) wcv[j] = w[j];
    }
    float w1[80];
    {
        int k = t / 80, g = t - (t / 80) * 80;
        const float* w = l1W + (size_t)(k * 80) * 80 + g;
        #pragma unroll
        for (int f = 0; f < 80; ++f) w1[f] = w[f * 80];
    }
    float bcv  = (t < 200) ? convb[t] : 0.0f;
    float b1   = l1b[t];
    float b1k3 = l1b[256 + (t & 63)];          // bias for l1 outputs 256..319

    // ---- LDS prefetch of small weights (drains during Phase 0/1) -----------
    for (int i = t; i < 840; i += 256) semb[i] = embW[i];
    if (t < 120) sembb[t] = embb[t];
    for (int i = t; i < 480; i += 256) {
        float v = (i < 80) ? oWs[i] : (i < 240) ? oWt[i - 80]
                : (i < 400) ? oWsc[i - 240] : oWtf[i - 400];
        shead[i] = v;
    }
    if (t < 6) sheadb[t] = (t == 0) ? obs[0] : (t < 3) ? obt[t-1]
                         : (t < 5) ? obsc[t-3] : obtf[0];

    const float bxmin = fminf(mx0, mx1) - 0.02f, bxmax = fmaxf(mx0, mx1) + 0.02f;
    const float bymin = fminf(my0, my1) - 0.02f, bymax = fmaxf(my0, my1) + 0.02f;

    // ---- Phase 0: cull from raw inputs; conic only for survivors -----------
    if (t == 0) cnt = 0;
    __syncthreads();
    for (int g = t; g < NG; g += 256) {
        float gmx = means[2*g], gmy = means[2*g+1];
        float s0  = scal[2*g],  s1  = scal[2*g+1];
        float tt  = trans[g];
        float c00 = s0*s0, c01 = s0*tt, c11 = tt*tt + s1*s1;
        float r2  = 100.0f * (c00 + c11);          // q>100 culled
        float ddx = fmaxf(fmaxf(bxmin - gmx, gmx - bxmax), 0.0f);
        float ddy = fmaxf(fmaxf(bymin - gmy, gmy - bymax), 0.0f);
        if (ddx*ddx + ddy*ddy <= r2) {
            float idet = 1.0f / (c00*c11 - c01*c01);
            float A = c11*idet, B = -c01*idet, C = c00*idet;
            float alpha = 1.0f / (1.0f + __expf(-opac[g]));
            int slot = atomicAdd(&cnt, 1);
            float4* dst = (float4*)(gcomp + slot*8);
            dst[0] = make_float4(gmx, gmy, A, B);
            dst[1] = make_float4(C, A + C, alpha * u[g], 0.0f);
        }
    }
    __syncthreads();
    const int nsurv = cnt;

    // ---- Phase 1: pairwise. wave w: gaussian l=w>>1; chunk=(w&1)*2+lanehalf.
    {
        int w = t >> 6, lane = t & 63;
        int l = w >> 1;
        int hc = ((w & 1) << 1) | (lane >> 5);
        int s  = lane & 31; if (s > 24) s = 24;     // lanes 25-31 redundant
        int si = s / 5, sj = s - si * 5;
        float gx = l ? mx1 : mx0, gy = l ? my1 : my0;
        float sx = gx + (float)(si - 2) * 0.01f;
        float sy = gy + (float)(sj - 2) * 0.01f;
        float us = 0.0f, lp = 0.0f;
        #pragma unroll 2
        for (int i = hc; i < nsurv; i += 4) {
            float4 a = *(const float4*)(gcomp + i*8);
            float4 b = *(const float4*)(gcomp + i*8 + 4);
            float dx = sx - a.x, dy = sy - a.y;
            float Cq0 = a.z*dx + a.w*dy;
            float Cq1 = a.w*dx + b.x*dy;
            float q   = dx*Cq0 + dy*Cq1;
            float e   = __expf(-0.5f*q) * b.z;     // G * alpha * u
            us += e;
            lp += e * (Cq0*Cq0 + Cq1*Cq1 - b.y);
        }
        us += __shfl_down(us, 32);                 // combine lane-half chunks
        lp += __shfl_down(lp, 32);
        if ((lane & 31) == s && lane < 32) {       // lanes 0..24 only
            pus[l][w & 1][s] = us; plap[l][w & 1][s] = lp;
        }
    }
    __syncthreads();

    // ---- Phase A: combine 2 wave-partials -> img[2][75] ---------------------
    if (t < 50) {
        int l = t / 25, s = t - l * 25;
        float us = pus[l][0][s] + pus[l][1][s];
        float lp = plap[l][0][s] + plap[l][1][s];
        int si = s / 5, sj = s - si * 5;
        float gx = l ? mx1 : mx0, gy = l ? my1 : my0;
        float sx = gx + (float)(si - 2) * 0.01f;
        float sy = gy + (float)(sj - 2) * 0.01f;
        simg[l][s]      = us;
        simg[l][25 + s] = lp;
        simg[l][50 + s] = (fabsf(sx) < 1.0f && fabsf(sy) < 1.0f) ? 1.0f : 0.0f;
    }
    __syncthreads();

    // ---- Phase B: conv from registers (x2) + emb from LDS -------------------
    if (t < 200) {
        float a0 = bcv, a1 = bcv;
        #pragma unroll
        for (int j = 0; j < 75; ++j) {
            a0 += simg[0][j] * wcv[j];
            a1 += simg[1][j] * wcv[j];
        }
        int k = t / 50, o = t - k * 50;
        hin[0][k][o] = tanh_fast(a0);
        hin[1][k][o] = tanh_fast(a1);
    } else {
        for (int idx = t - 200; idx < 240; idx += 56) {
            int l = idx / 120, rem = idx - l * 120;
            int k = rem / 30, g = rem - k * 30;
            float acc = sembb[k * 30 + g];
            #pragma unroll
            for (int f = 0; f < 7; ++f) {
                float in0, in1;
                switch (f) {
                    case 0: in0 = mx0;  in1 = mx1;  break;
                    case 1: in0 = my0;  in1 = my1;  break;
                    case 2: in0 = uu0;  in1 = uu1;  break;
                    case 3: in0 = sc00; in1 = sc10; break;
                    case 4: in0 = sc01; in1 = sc11; break;
                    case 5: in0 = tr0;  in1 = tr1;  break;
                    default: in0 = op0; in1 = op1;  break;
                }
                acc += (l ? in1 : in0) * semb[(k*7 + f)*30 + g];
            }
            hin[l][k][50 + g] = tanh_fast(acc);
        }
    }
    __syncthreads();

    // ---- Phase C: l1. Outputs 0..255 from registers; 256..319 from L2 -------
    {
        int k = t / 80, g = t - (t / 80) * 80;
        float a0 = b1, a1 = b1;
        #pragma unroll
        for (int f = 0; f < 80; ++f) {
            a0 += hin[0][k][f] * w1[f];
            a1 += hin[1][k][f] * w1[f];
        }
        hv[0][k][g] = tanh_fast(a0);
        hv[1][k][g] = tanh_fast(a1);
    }
    if (t < 64) {                                   // outputs 256..319: k=3
        int g = 16 + t;
        float a0 = b1k3, a1 = b1k3;
        #pragma unroll 8
        for (int f = 0; f < 80; ++f) {
            float w = l1W[(3*80 + f)*80 + g];
            a0 += hin[0][3][f] * w;
            a1 += hin[1][3][f] * w;
        }
        hv[0][3][g] = tanh_fast(a0);
        hv[1][3][g] = tanh_fast(a1);
    }
    __syncthreads();

    // ---- Phase D+E: heads from LDS + finalize, wave 0, shfl gather ----------
    if (t < 64) {
        int l = (t / 6) & 1, t6 = t % 6;            // lanes 12-63 redundant
        int k, base, stride, j;
        if (t6 == 0)      { k = 0; base = 0;   stride = 1; j = 0; }
        else if (t6 < 3)  { k = 1; base = 80;  stride = 2; j = t6 - 1; }
        else if (t6 < 5)  { k = 2; base = 240; stride = 2; j = t6 - 3; }
        else              { k = 3; base = 400; stride = 1; j = 0; }
        float acc = sheadb[t6];
        #pragma unroll 8
        for (int f = 0; f < 80; ++f)
            acc += hv[l][k][f] * shead[base + f * stride + j];

        int sb = (t / 6) * 6;
        float o0 = __shfl(acc, sb + 0);
        float o1 = __shfl(acc, sb + 1);
        float o2 = __shfl(acc, sb + 2);
        float o3 = __shfl(acc, sb + 3);
        float o4 = __shfl(acc, sb + 4);
        float o5 = __shfl(acc, sb + 5);

        if (t == 0 || t == 6) {
            int n = n0 + (t / 6);
            float uu = t ? uu1 : uu0;
            float s0 = t ? sc10 : sc00, s1 = t ? sc11 : sc01;
            float tr = t ? tr1 : tr0;
            float u_new = uu + o0;
            float mxn = (t ? mx1 : mx0) + o1;
            float myn = (t ? my1 : my0) + o2;
            float s0n = s0 * __expf(o3);
            float s1n = s1 * __expf(o4);
            float tn  = tr + o5;
            float c00 = s0n*s0n, c01 = s0n*tn, c11 = tn*tn + s1n*s1n;
            out[n]              = u_new;   // u_new         @0
            out[1024 + 2*n]     = mxn;     // means_new     @1024
            out[1024 + 2*n + 1] = myn;
            out[3072 + 2*n]     = s0n;     // scaling_new   @3072
            out[3072 + 2*n + 1] = s1n;
            out[5120 + n]       = tn;      // transform_new @5120
            out[6144 + 4*n]     = c00;     // cov_new       @6144
            out[6144 + 4*n + 1] = c01;
            out[6144 + 4*n + 2] = c01;
            out[6144 + 4*n + 3] = c11;
        }
    }
}

// ---------------------------------------------------------------- launch
extern "C" void kernel_launch(void* const* d_in, const int* in_sizes, int n_in,
                              void* d_out, int out_size, void* d_ws, size_t ws_size,
                              hipStream_t stream)
{
    k_fused<<<dim3(NG / 2), dim3(256), 0, stream>>>(
        (const float*)d_in[0],  (const float*)d_in[1],  (const float*)d_in[2],
        (const float*)d_in[3],  (const float*)d_in[4],  (const float*)d_in[5],
        (const float*)d_in[6],  (const float*)d_in[7],  (const float*)d_in[8],
        (const float*)d_in[9],  (const float*)d_in[10], (const float*)d_in[11],
        (const float*)d_in[12], (const float*)d_in[13], (const float*)d_in[14],
        (const float*)d_in[15], (const float*)d_in[16], (const float*)d_in[17],
        (const float*)d_in[18], (float*)d_out);
}